// Round 1
// baseline (258.095 us; speedup 1.0000x reference)
//
#include <hip/hip_runtime.h>
#include <hip/hip_bf16.h>

#define P_CLS 512
#define D_DIM 2048
#define CAP   32
#define CHUNK 8
#define TAU_INV 2.0f

typedef short short8 __attribute__((ext_vector_type(8)));
typedef float f32x4 __attribute__((ext_vector_type(4)));

__device__ __forceinline__ float wave_red_sum(float v) {
#pragma unroll
  for (int o = 32; o > 0; o >>= 1) v += __shfl_down(v, o, 64);
  return v;
}
__device__ __forceinline__ float wave_red_max(float v) {
#pragma unroll
  for (int o = 32; o > 0; o >>= 1) v = fmaxf(v, __shfl_down(v, o, 64));
  return v;
}

__global__ void k_init(int* cnt, float* accs) {
  int t = blockIdx.x * blockDim.x + threadIdx.x;
  if (t < P_CLS) cnt[t] = 0;
  if (t < 8) accs[t] = 0.f;
}

__global__ void k_index(const int* __restrict__ label, int* __restrict__ cnt,
                        int* __restrict__ idx, int n) {
  int i = blockIdx.x * blockDim.x + threadIdx.x;
  if (i < n) {
    int p = label[i];
    int slot = atomicAdd(&cnt[p], 1);
    if (slot < CAP) idx[p * CAP + slot] = i;
  }
}

// One block per (class p = blockIdx.x, modality m = blockIdx.y).
// Stages CHUNK rows in registers (8 floats/thread/row), computes row norms via
// block reduction, accumulates s = sum(f/||f||), then writes bf16 center s/||s||
// and atomically adds ||s|| into accs[0].
__global__ __launch_bounds__(256)
void k_centers(const float* __restrict__ f0, const float* __restrict__ f1,
               const float* __restrict__ f2, const int* __restrict__ cnt,
               const int* __restrict__ idx, __hip_bfloat16* __restrict__ cb,
               float* __restrict__ accs) {
  __shared__ float red[4 * CHUNK];
  int p = blockIdx.x, m = blockIdx.y;
  const float* F = (m == 0) ? f0 : (m == 1) ? f1 : f2;
  int t = threadIdx.x;
  int lane = t & 63, wv = t >> 6;
  int c = cnt[p];
  if (c > CAP) c = CAP;
  const int* idxp = idx + p * CAP;
  f32x4 a0 = {0.f, 0.f, 0.f, 0.f}, a1 = {0.f, 0.f, 0.f, 0.f};
  for (int base = 0; base < c; base += CHUNK) {
    f32x4 v0[CHUNK], v1[CHUNK];
    float ssq[CHUNK];
#pragma unroll
    for (int r = 0; r < CHUNK; ++r) {
      int rr = base + r; if (rr >= c) rr = c - 1;   // pad with dup row, masked later
      long row = idxp[rr];
      const f32x4* src = (const f32x4*)(F + row * D_DIM);
      v0[r] = src[t];          // cols 4t   .. 4t+3
      v1[r] = src[t + 256];    // cols 1024+4t ..
      f32x4 q0 = v0[r] * v0[r], q1 = v1[r] * v1[r];
      ssq[r] = q0.x + q0.y + q0.z + q0.w + q1.x + q1.y + q1.z + q1.w;
    }
    __syncthreads();   // protect red[] reads from previous chunk
#pragma unroll
    for (int r = 0; r < CHUNK; ++r) {
      float v = wave_red_sum(ssq[r]);
      if (lane == 0) red[wv * CHUNK + r] = v;
    }
    __syncthreads();
#pragma unroll
    for (int r = 0; r < CHUNK; ++r) {
      float s = red[r] + red[CHUNK + r] + red[2 * CHUNK + r] + red[3 * CHUNK + r];
      float w = (base + r < c) ? (1.0f / fmaxf(sqrtf(s), 1e-12f)) : 0.0f;
      a0 += v0[r] * w;
      a1 += v1[r] * w;
    }
  }
  f32x4 q0 = a0 * a0, q1 = a1 * a1;
  float loc = q0.x + q0.y + q0.z + q0.w + q1.x + q1.y + q1.z + q1.w;
  loc = wave_red_sum(loc);
  __syncthreads();
  if (lane == 0) red[wv] = loc;
  __syncthreads();
  float snorm = sqrtf(red[0] + red[1] + red[2] + red[3]);
  float inv = 1.0f / fmaxf(snorm, 1e-12f);
  __hip_bfloat16* dst = cb + ((long)m * P_CLS + p) * D_DIM;
  int c0 = t * 4, c1 = D_DIM / 2 + t * 4;
  dst[c0 + 0] = __float2bfloat16(a0.x * inv);
  dst[c0 + 1] = __float2bfloat16(a0.y * inv);
  dst[c0 + 2] = __float2bfloat16(a0.z * inv);
  dst[c0 + 3] = __float2bfloat16(a0.w * inv);
  dst[c1 + 0] = __float2bfloat16(a1.x * inv);
  dst[c1 + 1] = __float2bfloat16(a1.y * inv);
  dst[c1 + 2] = __float2bfloat16(a1.z * inv);
  dst[c1 + 3] = __float2bfloat16(a1.w * inv);
  if (t == 0) atomicAdd(&accs[0], snorm);
}

// logits[pair][p][q] = (c_ma[p] . c_mb[q]) / TAU, bf16 MFMA, 64x64 tiles.
__global__ __launch_bounds__(256)
void k_gemm(const __hip_bfloat16* __restrict__ cbh, float* __restrict__ logits) {
  __shared__ __align__(16) unsigned short As[64 * 40], Bs[64 * 40];  // stride 40: <=2-way banks
  int pair = blockIdx.y;
  int ma = (pair == 2) ? 1 : 0;
  int mb = (pair == 0) ? 1 : 2;
  const unsigned short* A = (const unsigned short*)cbh + (long)ma * P_CLS * D_DIM;
  const unsigned short* B = (const unsigned short*)cbh + (long)mb * P_CLS * D_DIM;
  float* C = logits + (long)pair * P_CLS * P_CLS;
  int tm = (blockIdx.x >> 3) * 64;
  int tn = (blockIdx.x & 7) * 64;
  int t = threadIdx.x, lane = t & 63, wv = t >> 6;
  int srow = t >> 2, skc = (t & 3) * 8;   // staging: 4 threads x 16B per 32-col row
  int quad = lane >> 4, mr = lane & 15;
  f32x4 acc[4] = {{0,0,0,0},{0,0,0,0},{0,0,0,0},{0,0,0,0}};
  for (int k0 = 0; k0 < D_DIM; k0 += 32) {
    uint4 av = *(const uint4*)(A + (long)(tm + srow) * D_DIM + k0 + skc);
    uint4 bv = *(const uint4*)(B + (long)(tn + srow) * D_DIM + k0 + skc);
    __syncthreads();
    *(uint4*)(As + srow * 40 + skc) = av;
    *(uint4*)(Bs + srow * 40 + skc) = bv;
    __syncthreads();
    // A-frag: row (wv*16+mr) of tile, k = quad*8..+7 ; B-frag: row (col) nb*16+mr
    short8 af = *(const short8*)(As + (wv * 16 + mr) * 40 + quad * 8);
#pragma unroll
    for (int nb = 0; nb < 4; ++nb) {
      short8 bfr = *(const short8*)(Bs + (nb * 16 + mr) * 40 + quad * 8);
      acc[nb] = __builtin_amdgcn_mfma_f32_16x16x32_bf16(af, bfr, acc[nb], 0, 0, 0);
    }
  }
  // C/D layout: col = lane&15, row = quad*4 + reg
  int crow = tm + wv * 16 + quad * 4;
#pragma unroll
  for (int nb = 0; nb < 4; ++nb)
#pragma unroll
    for (int r = 0; r < 4; ++r)
      C[(long)(crow + r) * P_CLS + tn + nb * 16 + mr] = acc[nb][r] * TAU_INV;
}

// One block per (pair,p) row of logits: accumulate (logsumexp - diag).
__global__ __launch_bounds__(256)
void k_lse(const float* __restrict__ logits, float* __restrict__ accs) {
  __shared__ float sred[8];
  int row = blockIdx.x;            // 0 .. 3*P-1
  int p = row & (P_CLS - 1);
  const float* L = logits + (long)row * P_CLS;
  int t = threadIdx.x, lane = t & 63, wv = t >> 6;
  float v0 = L[t], v1 = L[t + 256];
  float mx = wave_red_max(fmaxf(v0, v1));
  if (lane == 0) sred[wv] = mx;
  __syncthreads();
  mx = fmaxf(fmaxf(sred[0], sred[1]), fmaxf(sred[2], sred[3]));
  float e = expf(v0 - mx) + expf(v1 - mx);
  e = wave_red_sum(e);
  if (lane == 0) sred[4 + wv] = e;
  __syncthreads();
  if (t == 0) {
    float tot = sred[4] + sred[5] + sred[6] + sred[7];
    atomicAdd(&accs[1], mx + logf(tot) - L[p]);
  }
}

__global__ void k_final(const float* __restrict__ accs, float* __restrict__ out,
                        float invN) {
  out[0] = 6.0f - 2.0f * invN * accs[0] + accs[1] * (1.0f / (float)P_CLS);
}

extern "C" void kernel_launch(void* const* d_in, const int* in_sizes, int n_in,
                              void* d_out, int out_size, void* d_ws, size_t ws_size,
                              hipStream_t stream) {
  const float* fvp = (const float*)d_in[0];
  const float* fap = (const float*)d_in[1];
  const float* frp = (const float*)d_in[2];
  const int* label = (const int*)d_in[3];
  int N = in_sizes[3];

  char* ws = (char*)d_ws;
  int* cnt = (int*)ws;                                    // 2048 B
  int* idx = (int*)(ws + 2048);                           // 512*32*4 = 64 KiB
  float* accs = (float*)(ws + 2048 + 65536);              // 32 B
  __hip_bfloat16* cb = (__hip_bfloat16*)(ws + 131072);    // 3*P*D*2 = 6 MiB
  float* logits = (float*)(ws + 131072 + 3ul * P_CLS * D_DIM * 2);  // 3 MiB

  hipLaunchKernelGGL(k_init, dim3(1), dim3(512), 0, stream, cnt, accs);
  hipLaunchKernelGGL(k_index, dim3((N + 255) / 256), dim3(256), 0, stream,
                     label, cnt, idx, N);
  hipLaunchKernelGGL(k_centers, dim3(P_CLS, 3), dim3(256), 0, stream,
                     fvp, fap, frp, cnt, idx, cb, accs);
  hipLaunchKernelGGL(k_gemm, dim3(64, 3), dim3(256), 0, stream, cb, logits);
  hipLaunchKernelGGL(k_lse, dim3(3 * P_CLS), dim3(256), 0, stream, logits, accs);
  hipLaunchKernelGGL(k_final, dim3(1), dim3(1), 0, stream, accs, (float*)d_out,
                     1.0f / (float)N);
}

// Round 3
// 248.953 us; speedup vs baseline: 1.0367x; 1.0367x over previous
//
#include <hip/hip_runtime.h>
#include <hip/hip_bf16.h>

#define P_CLS 512
#define D_DIM 2048
#define CAP   32
#define TAU_INV 2.0f

typedef short short8 __attribute__((ext_vector_type(8)));
typedef float f32x4 __attribute__((ext_vector_type(4)));

__device__ __forceinline__ unsigned short f2bf_bits(float x) {
  __hip_bfloat16 b = __float2bfloat16(x);
  unsigned short u;
  __builtin_memcpy(&u, &b, sizeof(u));
  return u;
}

__device__ __forceinline__ float xred_sum(float v) {
#pragma unroll
  for (int o = 1; o < 64; o <<= 1) v += __shfl_xor(v, o, 64);
  return v;  // all lanes hold the total
}
__device__ __forceinline__ float xred_max(float v) {
#pragma unroll
  for (int o = 1; o < 64; o <<= 1) v = fmaxf(v, __shfl_xor(v, o, 64));
  return v;
}

__global__ void k_init(int* cnt, float* accs) {
  int t = blockIdx.x * blockDim.x + threadIdx.x;
  if (t < P_CLS) cnt[t] = 0;
  if (t < 8) accs[t] = 0.f;
}

__global__ void k_index(const int* __restrict__ label, int* __restrict__ cnt,
                        int* __restrict__ idx, int n) {
  int i = blockIdx.x * blockDim.x + threadIdx.x;
  if (i < n) {
    int p = label[i];
    int slot = atomicAdd(&cnt[p], 1);
    if (slot < CAP) idx[p * CAP + slot] = i;
  }
}

// One WAVE per (class, modality). Lane owns cols lane*4 + k*256 (+0..3),
// k=0..7 => 32 floats/lane accumulator. Rows software-pipelined (ping-pong);
// no __syncthreads anywhere.
__global__ __launch_bounds__(128)
void k_centers(const float* __restrict__ f0, const float* __restrict__ f1,
               const float* __restrict__ f2, const int* __restrict__ cnt,
               const int* __restrict__ idx, __hip_bfloat16* __restrict__ cb,
               float* __restrict__ accs) {
  int wv = threadIdx.x >> 6, lane = threadIdx.x & 63;
  int p = blockIdx.x * 2 + wv;
  int m = blockIdx.y;
  const float* F = (m == 0) ? f0 : (m == 1) ? f1 : f2;
  int c = cnt[p];
  if (c > CAP) c = CAP;
  const int* idxp = idx + p * CAP;
  __hip_bfloat16* dst = cb + ((long)m * P_CLS + p) * D_DIM;

  f32x4 acc[8] = {};
  if (c > 0) {
    f32x4 v[8], nv[8];
    const f32x4* rp = (const f32x4*)(F + (long)idxp[0] * D_DIM);
#pragma unroll
    for (int k = 0; k < 8; ++k) v[k] = rp[lane + k * 64];
    for (int r = 0; r < c; ++r) {
      if (r + 1 < c) {
        const f32x4* np = (const f32x4*)(F + (long)idxp[r + 1] * D_DIM);
#pragma unroll
        for (int k = 0; k < 8; ++k) nv[k] = np[lane + k * 64];
      }
      float ssq = 0.f;
#pragma unroll
      for (int k = 0; k < 8; ++k) {
        f32x4 q = v[k] * v[k];
        ssq += q.x + q.y + q.z + q.w;
      }
      ssq = xred_sum(ssq);
      float w = 1.0f / fmaxf(sqrtf(ssq), 1e-12f);
#pragma unroll
      for (int k = 0; k < 8; ++k) acc[k] += v[k] * w;
#pragma unroll
      for (int k = 0; k < 8; ++k) v[k] = nv[k];
    }
  }
  float s2 = 0.f;
#pragma unroll
  for (int k = 0; k < 8; ++k) {
    f32x4 q = acc[k] * acc[k];
    s2 += q.x + q.y + q.z + q.w;
  }
  s2 = xred_sum(s2);
  float sn = sqrtf(s2);
  float inv = 1.0f / fmaxf(sn, 1e-12f);
#pragma unroll
  for (int k = 0; k < 8; ++k) {
    f32x4 o = acc[k] * inv;
    ushort4 h;
    h.x = f2bf_bits(o.x);
    h.y = f2bf_bits(o.y);
    h.z = f2bf_bits(o.z);
    h.w = f2bf_bits(o.w);
    ((ushort4*)dst)[lane + k * 64] = h;
  }
  if (lane == 0 && c > 0) atomicAdd(&accs[0], sn);
}

// Split-K(2) bf16 MFMA GEMM, 64x64 tiles, LDS double-buffer + depth-2 reg
// prefetch, ONE barrier per K-step. Partial z writes logits + z*3*P*P.
__global__ __launch_bounds__(256)
void k_gemm(const __hip_bfloat16* __restrict__ cbh, float* __restrict__ logits) {
  __shared__ __align__(16) unsigned short As[2][64 * 40], Bs[2][64 * 40];
  int pair = blockIdx.y, kz = blockIdx.z;
  int ma = (pair == 2) ? 1 : 0;
  int mb = (pair == 0) ? 1 : 2;
  const unsigned short* A =
      (const unsigned short*)cbh + (long)ma * P_CLS * D_DIM + kz * (D_DIM / 2);
  const unsigned short* B =
      (const unsigned short*)cbh + (long)mb * P_CLS * D_DIM + kz * (D_DIM / 2);
  float* C = logits + ((long)kz * 3 + pair) * P_CLS * P_CLS;
  int tm = (blockIdx.x >> 3) * 64, tn = (blockIdx.x & 7) * 64;
  int t = threadIdx.x, lane = t & 63, wv = t >> 6;
  int srow = t >> 2, skc = (t & 3) * 8;
  int quad = lane >> 4, mr = lane & 15;
  const unsigned short* pa = A + (long)(tm + srow) * D_DIM + skc;
  const unsigned short* pb = B + (long)(tn + srow) * D_DIM + skc;
  f32x4 acc[4] = {{0,0,0,0},{0,0,0,0},{0,0,0,0},{0,0,0,0}};
  uint4 av = *(const uint4*)pa, bv = *(const uint4*)pb;          // k-step 0
  *(uint4*)(&As[0][srow * 40 + skc]) = av;
  *(uint4*)(&Bs[0][srow * 40 + skc]) = bv;
  av = *(const uint4*)(pa + 32); bv = *(const uint4*)(pb + 32);  // k-step 1
  const int NIT = (D_DIM / 2) / 32;  // 32
  for (int it = 0; it < NIT; ++it) {
    __syncthreads();
    int cur = it & 1;
    if (it + 1 < NIT) {
      *(uint4*)(&As[cur ^ 1][srow * 40 + skc]) = av;
      *(uint4*)(&Bs[cur ^ 1][srow * 40 + skc]) = bv;
    }
    if (it + 2 < NIT) {
      av = *(const uint4*)(pa + (it + 2) * 32);
      bv = *(const uint4*)(pb + (it + 2) * 32);
    }
    short8 af = *(const short8*)(&As[cur][(wv * 16 + mr) * 40 + quad * 8]);
#pragma unroll
    for (int nb = 0; nb < 4; ++nb) {
      short8 bfr = *(const short8*)(&Bs[cur][(nb * 16 + mr) * 40 + quad * 8]);
      acc[nb] = __builtin_amdgcn_mfma_f32_16x16x32_bf16(af, bfr, acc[nb], 0, 0, 0);
    }
  }
  int crow = tm + wv * 16 + quad * 4;
#pragma unroll
  for (int nb = 0; nb < 4; ++nb)
#pragma unroll
    for (int r = 0; r < 4; ++r)
      C[(long)(crow + r) * P_CLS + tn + nb * 16 + mr] = acc[nb][r] * TAU_INV;
}

// One block per (pair,p) row: sum the two split-K partials, logsumexp - diag.
__global__ __launch_bounds__(256)
void k_lse(const float* __restrict__ logits, float* __restrict__ accs) {
  __shared__ float sred[8];
  int row = blockIdx.x;  // 0 .. 3*P-1
  int p = row & (P_CLS - 1);
  const float* L0 = logits + (long)row * P_CLS;
  const float* L1 = L0 + 3l * P_CLS * P_CLS;
  int t = threadIdx.x, lane = t & 63, wv = t >> 6;
  float v0 = L0[t] + L1[t];
  float v1 = L0[t + 256] + L1[t + 256];
  float mx = xred_max(fmaxf(v0, v1));
  if (lane == 0) sred[wv] = mx;
  __syncthreads();
  mx = fmaxf(fmaxf(sred[0], sred[1]), fmaxf(sred[2], sred[3]));
  float e = expf(v0 - mx) + expf(v1 - mx);
  e = xred_sum(e);
  if (lane == 0) sred[4 + wv] = e;
  __syncthreads();
  if (t == 0) {
    float tot = sred[4] + sred[5] + sred[6] + sred[7];
    float diag = L0[p] + L1[p];
    atomicAdd(&accs[1], mx + logf(tot) - diag);
  }
}

__global__ void k_final(const float* __restrict__ accs, float* __restrict__ out,
                        float invN) {
  out[0] = 6.0f - 2.0f * invN * accs[0] + accs[1] * (1.0f / (float)P_CLS);
}

extern "C" void kernel_launch(void* const* d_in, const int* in_sizes, int n_in,
                              void* d_out, int out_size, void* d_ws, size_t ws_size,
                              hipStream_t stream) {
  const float* fvp = (const float*)d_in[0];
  const float* fap = (const float*)d_in[1];
  const float* frp = (const float*)d_in[2];
  const int* label = (const int*)d_in[3];
  int N = in_sizes[3];

  char* ws = (char*)d_ws;
  int* cnt = (int*)ws;                                    // 2 KiB
  int* idx = (int*)(ws + 2048);                           // 64 KiB
  float* accs = (float*)(ws + 2048 + 65536);              // 32 B
  __hip_bfloat16* cb = (__hip_bfloat16*)(ws + 131072);    // 6 MiB
  float* logits = (float*)(ws + 131072 + 3ul * P_CLS * D_DIM * 2);  // 2 x 3 MiB

  hipLaunchKernelGGL(k_init, dim3(1), dim3(512), 0, stream, cnt, accs);
  hipLaunchKernelGGL(k_index, dim3((N + 255) / 256), dim3(256), 0, stream,
                     label, cnt, idx, N);
  hipLaunchKernelGGL(k_centers, dim3(P_CLS / 2, 3), dim3(128), 0, stream,
                     fvp, fap, frp, cnt, idx, cb, accs);
  hipLaunchKernelGGL(k_gemm, dim3(64, 3, 2), dim3(256), 0, stream, cb, logits);
  hipLaunchKernelGGL(k_lse, dim3(3 * P_CLS), dim3(256), 0, stream, logits, accs);
  hipLaunchKernelGGL(k_final, dim3(1), dim3(1), 0, stream, accs, (float*)d_out,
                     1.0f / (float)N);
}

// Round 4
// 239.662 us; speedup vs baseline: 1.0769x; 1.0388x over previous
//
#include <hip/hip_runtime.h>
#include <hip/hip_bf16.h>

#define P_CLS 512
#define D_DIM 2048
#define CAP   32
#define TAU_INV 2.0f

typedef short short8 __attribute__((ext_vector_type(8)));
typedef float f32x4 __attribute__((ext_vector_type(4)));

__device__ __forceinline__ unsigned short f2bf_bits(float x) {
  __hip_bfloat16 b = __float2bfloat16(x);
  unsigned short u;
  __builtin_memcpy(&u, &b, sizeof(u));
  return u;
}

__device__ __forceinline__ void async16(const void* g, void* l) {
  __builtin_amdgcn_global_load_lds(
      (const __attribute__((address_space(1))) void*)g,
      (__attribute__((address_space(3))) void*)l, 16, 0, 0);
}

__device__ __forceinline__ float xred_sum(float v) {
#pragma unroll
  for (int o = 1; o < 64; o <<= 1) v += __shfl_xor(v, o, 64);
  return v;
}
__device__ __forceinline__ float xred_max(float v) {
#pragma unroll
  for (int o = 1; o < 64; o <<= 1) v = fmaxf(v, __shfl_xor(v, o, 64));
  return v;
}

__global__ void k_init(int* cnt, float* accs) {
  int t = blockIdx.x * blockDim.x + threadIdx.x;
  if (t < P_CLS) cnt[t] = 0;
  if (t < 8) accs[t] = 0.f;
}

__global__ void k_index(const int* __restrict__ label, int* __restrict__ cnt,
                        int* __restrict__ idx, int n) {
  int i = blockIdx.x * blockDim.x + threadIdx.x;
  if (i < n) {
    int p = label[i];
    int slot = atomicAdd(&cnt[p], 1);
    if (slot < CAP) idx[p * CAP + slot] = i;
  }
}

// Block of 256 per (class p, modality m). 8-row chunks staged to LDS via
// global_load_lds width=16 (no VGPR cost -> deep async queue). Compute:
// per-row norms (wave-sliced) then weighted accumulate, both conflict-free
// b128 LDS reads. 64 KB LDS -> 2 blocks/CU overlap staging<->compute.
__global__ __launch_bounds__(256)
void k_centers(const float* __restrict__ f0, const float* __restrict__ f1,
               const float* __restrict__ f2, const int* __restrict__ cnt,
               const int* __restrict__ idx, __hip_bfloat16* __restrict__ cb,
               float* __restrict__ accs) {
  __shared__ __align__(16) float rows[8 * D_DIM];  // 64 KiB
  __shared__ float scr[16];
  int p = blockIdx.x, m = blockIdx.y;
  const float* F = (m == 0) ? f0 : (m == 1) ? f1 : f2;
  int t = threadIdx.x, lane = t & 63, wv = t >> 6;
  int c = cnt[p];
  if (c > CAP) c = CAP;
  const int* idxp = idx + p * CAP;

  f32x4 acc0 = {0, 0, 0, 0}, acc1 = {0, 0, 0, 0};
  for (int base = 0; base < c; base += 8) {
    // --- stage: wave wv stages rows 2wv, 2wv+1 (8 x 1KB chunks each) ---
#pragma unroll
    for (int s = 0; s < 2; ++s) {
      int rr = 2 * wv + s, gr = base + rr;
      if (gr < c) {
        const char* rowp = (const char*)(F + (long)idxp[gr] * D_DIM);
        char* ldsp = (char*)(rows + rr * D_DIM);
#pragma unroll
        for (int j = 0; j < 8; ++j)
          async16(rowp + j * 1024 + lane * 16, ldsp + j * 1024 + lane * 16);
      }
    }
    __syncthreads();
    // --- row norms: wave wv reduces rows 2wv, 2wv+1 ---
#pragma unroll
    for (int s = 0; s < 2; ++s) {
      int rr = 2 * wv + s;
      const f32x4* rp = (const f32x4*)(rows + rr * D_DIM);
      float ssq = 0.f;
#pragma unroll
      for (int j = 0; j < 8; ++j) {
        f32x4 q = rp[lane + 64 * j];
        q = q * q;
        ssq += q.x + q.y + q.z + q.w;
      }
      ssq = xred_sum(ssq);
      if (lane == 0)
        scr[rr] = (base + rr < c) ? (1.0f / fmaxf(sqrtf(ssq), 1e-12f)) : 0.f;
    }
    __syncthreads();
    // --- weighted accumulate: thread t owns cols 4t and 1024+4t ---
#pragma unroll
    for (int rr = 0; rr < 8; ++rr) {
      float w = scr[rr];
      f32x4 x0 = *(const f32x4*)(rows + rr * D_DIM + t * 4);
      f32x4 x1 = *(const f32x4*)(rows + rr * D_DIM + 1024 + t * 4);
      acc0 += x0 * w;
      acc1 += x1 * w;
    }
    __syncthreads();  // before next chunk overwrites rows/scr
  }
  f32x4 q0 = acc0 * acc0, q1 = acc1 * acc1;
  float s2 = q0.x + q0.y + q0.z + q0.w + q1.x + q1.y + q1.z + q1.w;
  s2 = xred_sum(s2);
  if (lane == 0) scr[8 + wv] = s2;
  __syncthreads();
  s2 = scr[8] + scr[9] + scr[10] + scr[11];
  float sn = sqrtf(s2);
  float inv = 1.0f / fmaxf(sn, 1e-12f);
  __hip_bfloat16* dst = cb + ((long)m * P_CLS + p) * D_DIM;
  f32x4 o0 = acc0 * inv, o1 = acc1 * inv;
  ushort4 h0, h1;
  h0.x = f2bf_bits(o0.x); h0.y = f2bf_bits(o0.y);
  h0.z = f2bf_bits(o0.z); h0.w = f2bf_bits(o0.w);
  h1.x = f2bf_bits(o1.x); h1.y = f2bf_bits(o1.y);
  h1.z = f2bf_bits(o1.z); h1.w = f2bf_bits(o1.w);
  ((ushort4*)dst)[t] = h0;
  ((ushort4*)dst)[t + 256] = h1;
  if (t == 0 && c > 0) atomicAdd(&accs[0], sn);
}

// Split-K bf16 MFMA GEMM (gridDim.z slices), 64x64 tiles, LDS double-buffer
// + depth-2 reg prefetch, one barrier per K-step.
__global__ __launch_bounds__(256)
void k_gemm(const __hip_bfloat16* __restrict__ cbh, float* __restrict__ logits) {
  __shared__ __align__(16) unsigned short As[2][64 * 40], Bs[2][64 * 40];
  int pair = blockIdx.y, kz = blockIdx.z, nkz = gridDim.z;
  int ksl = D_DIM / nkz;
  int ma = (pair == 2) ? 1 : 0;
  int mb = (pair == 0) ? 1 : 2;
  const unsigned short* A =
      (const unsigned short*)cbh + (long)ma * P_CLS * D_DIM + kz * ksl;
  const unsigned short* B =
      (const unsigned short*)cbh + (long)mb * P_CLS * D_DIM + kz * ksl;
  float* C = logits + ((long)kz * 3 + pair) * P_CLS * P_CLS;
  int tm = (blockIdx.x >> 3) * 64, tn = (blockIdx.x & 7) * 64;
  int t = threadIdx.x, lane = t & 63, wv = t >> 6;
  int srow = t >> 2, skc = (t & 3) * 8;
  int quad = lane >> 4, mr = lane & 15;
  const unsigned short* pa = A + (long)(tm + srow) * D_DIM + skc;
  const unsigned short* pb = B + (long)(tn + srow) * D_DIM + skc;
  f32x4 acc[4] = {{0,0,0,0},{0,0,0,0},{0,0,0,0},{0,0,0,0}};
  uint4 av = *(const uint4*)pa, bv = *(const uint4*)pb;
  *(uint4*)(&As[0][srow * 40 + skc]) = av;
  *(uint4*)(&Bs[0][srow * 40 + skc]) = bv;
  av = *(const uint4*)(pa + 32); bv = *(const uint4*)(pb + 32);
  const int NIT = ksl / 32;
  for (int it = 0; it < NIT; ++it) {
    __syncthreads();
    int cur = it & 1;
    if (it + 1 < NIT) {
      *(uint4*)(&As[cur ^ 1][srow * 40 + skc]) = av;
      *(uint4*)(&Bs[cur ^ 1][srow * 40 + skc]) = bv;
    }
    if (it + 2 < NIT) {
      av = *(const uint4*)(pa + (it + 2) * 32);
      bv = *(const uint4*)(pb + (it + 2) * 32);
    }
    short8 af = *(const short8*)(&As[cur][(wv * 16 + mr) * 40 + quad * 8]);
#pragma unroll
    for (int nb = 0; nb < 4; ++nb) {
      short8 bfr = *(const short8*)(&Bs[cur][(nb * 16 + mr) * 40 + quad * 8]);
      acc[nb] = __builtin_amdgcn_mfma_f32_16x16x32_bf16(af, bfr, acc[nb], 0, 0, 0);
    }
  }
  int crow = tm + wv * 16 + quad * 4;
#pragma unroll
  for (int nb = 0; nb < 4; ++nb)
#pragma unroll
    for (int r = 0; r < 4; ++r)
      C[(long)(crow + r) * P_CLS + tn + nb * 16 + mr] = acc[nb][r] * TAU_INV;
}

// One block per (pair,p) row: sum nkz split-K partials, logsumexp - diag.
__global__ __launch_bounds__(256)
void k_lse(const float* __restrict__ logits, float* __restrict__ accs, int nkz) {
  __shared__ float sred[8];
  int row = blockIdx.x;  // 0 .. 3*P-1
  int p = row & (P_CLS - 1);
  int t = threadIdx.x, lane = t & 63, wv = t >> 6;
  float v0 = 0.f, v1 = 0.f, diag = 0.f;
  for (int z = 0; z < nkz; ++z) {
    const float* L = logits + ((long)z * 3 * P_CLS + row) * P_CLS;
    v0 += L[t];
    v1 += L[t + 256];
  }
  float mx = xred_max(fmaxf(v0, v1));
  if (lane == 0) sred[wv] = mx;
  __syncthreads();
  mx = fmaxf(fmaxf(sred[0], sred[1]), fmaxf(sred[2], sred[3]));
  float e = expf(v0 - mx) + expf(v1 - mx);
  e = xred_sum(e);
  if (lane == 0) sred[4 + wv] = e;
  __syncthreads();
  if (t == 0) {
    float tot = sred[4] + sred[5] + sred[6] + sred[7];
    for (int z = 0; z < nkz; ++z)
      diag += logits[((long)z * 3 * P_CLS + row) * P_CLS + p];
    atomicAdd(&accs[1], mx + logf(tot) - diag);
  }
}

__global__ void k_final(const float* __restrict__ accs, float* __restrict__ out,
                        float invN) {
  out[0] = 6.0f - 2.0f * invN * accs[0] + accs[1] * (1.0f / (float)P_CLS);
}

extern "C" void kernel_launch(void* const* d_in, const int* in_sizes, int n_in,
                              void* d_out, int out_size, void* d_ws, size_t ws_size,
                              hipStream_t stream) {
  const float* fvp = (const float*)d_in[0];
  const float* fap = (const float*)d_in[1];
  const float* frp = (const float*)d_in[2];
  const int* label = (const int*)d_in[3];
  int N = in_sizes[3];

  char* ws = (char*)d_ws;
  int* cnt = (int*)ws;                                    // 2 KiB
  int* idx = (int*)(ws + 2048);                           // 64 KiB
  float* accs = (float*)(ws + 2048 + 65536);              // 32 B
  __hip_bfloat16* cb = (__hip_bfloat16*)(ws + 131072);    // 6 MiB
  float* logits = (float*)(ws + 131072 + 3ul * P_CLS * D_DIM * 2);

  size_t base = 131072 + 3ul * P_CLS * D_DIM * 2;
  size_t per_z = 3ul * P_CLS * P_CLS * 4;
  int KZ = (ws_size >= base + 4 * per_z) ? 4 : 2;

  hipLaunchKernelGGL(k_init, dim3(1), dim3(512), 0, stream, cnt, accs);
  hipLaunchKernelGGL(k_index, dim3((N + 255) / 256), dim3(256), 0, stream,
                     label, cnt, idx, N);
  hipLaunchKernelGGL(k_centers, dim3(P_CLS, 3), dim3(256), 0, stream,
                     fvp, fap, frp, cnt, idx, cb, accs);
  hipLaunchKernelGGL(k_gemm, dim3(64, 3, KZ), dim3(256), 0, stream, cb, logits);
  hipLaunchKernelGGL(k_lse, dim3(3 * P_CLS), dim3(256), 0, stream, logits, accs, KZ);
  hipLaunchKernelGGL(k_final, dim3(1), dim3(1), 0, stream, accs, (float*)d_out,
                     1.0f / (float)N);
}